// Round 4
// baseline (980.730 us; speedup 1.0000x reference)
//
#include <hip/hip_runtime.h>

// ---------------- problem constants ----------------
#define DIMD 1024
#define BATCH 8
#define SEQ 4096
#define TCH 64                  // scan chunk length
#define NCH (SEQ / TCH)         // 64 chunks per sequence
#define GB 4                    // batches per group
#define NG (BATCH / GB)         // 2 groups
#define GTOK (GB * SEQ)         // 16384 tokens per group
#define NCHG (GB * DIMD)        // 4096 scan channels per group

typedef short short8 __attribute__((ext_vector_type(8)));
typedef unsigned short u16x8 __attribute__((ext_vector_type(8)));
typedef __bf16 bf16x8 __attribute__((ext_vector_type(8)));
typedef float f32x4 __attribute__((ext_vector_type(4)));

static __device__ __forceinline__ unsigned short f2bf(float f) {
    unsigned int u = __builtin_bit_cast(unsigned int, f);
    u += 0x7FFFu + ((u >> 16) & 1u);   // round-to-nearest-even
    return (unsigned short)(u >> 16);
}
static __device__ __forceinline__ float bf2f(unsigned short s) {
    return __builtin_bit_cast(float, ((unsigned int)s) << 16);
}

// ---------------- dtype detector ----------------
// If x is bf16, the low 16 bits of each u32 word are a bf16 ~N(0,1): exponent
// field in [0x70,0x8F] almost surely. If x is fp32, low 16 bits are uniform
// mantissa bits: ~12.5% hit that range. Count over 64 words, threshold 32.
__global__ void detect(const unsigned* __restrict__ xw, unsigned* __restrict__ flag) {
    if (threadIdx.x == 0 && blockIdx.x == 0) {
        int cnt = 0;
        for (int i = 0; i < 64; ++i) {
            unsigned lo = xw[i] & 0xFFFFu;
            unsigned e = (lo >> 7) & 0xFFu;
            if ((e >= 0x70u && e <= 0x8Fu) || lo == 0u) ++cnt;
        }
        *flag = (cnt >= 32) ? 1u : 0u;   // 1 = bf16 inputs, 0 = fp32 inputs
    }
}

// ---------------- small param vectors -> fp32 scratch ----------------
// dst layout: [u | w | tmk | tmv | tmr | bo], each 1024 floats
__global__ void cvt_small(const void* __restrict__ s0, const void* __restrict__ s1,
                          const void* __restrict__ s2, const void* __restrict__ s3,
                          const void* __restrict__ s4, const void* __restrict__ s5,
                          float* __restrict__ dst, const unsigned* __restrict__ flag) {
    const void* s;
    switch (blockIdx.y) {
        case 0: s = s0; break; case 1: s = s1; break; case 2: s = s2; break;
        case 3: s = s3; break; case 4: s = s4; break; default: s = s5; break;
    }
    int i = blockIdx.x * 256 + threadIdx.x;   // grid.x = 4 -> 0..1023
    float v = (*flag) ? bf2f(((const unsigned short*)s)[i]) : ((const float*)s)[i];
    dst[blockIdx.y * 1024 + i] = v;
}

// ---------------- weight matrices -> bf16 scratch (contiguous 4x 2MiB) ----------
__global__ void cvt_W(const void* __restrict__ s0, const void* __restrict__ s1,
                      const void* __restrict__ s2, const void* __restrict__ s3,
                      unsigned short* __restrict__ dst, const unsigned* __restrict__ flag) {
    const void* s;
    switch (blockIdx.y) {
        case 0: s = s0; break; case 1: s = s1; break;
        case 2: s = s2; break; default: s = s3; break;
    }
    unsigned short* d = dst + (size_t)blockIdx.y * DIMD * DIMD;
    size_t i8 = (size_t)blockIdx.x * 256 + threadIdx.x;   // grid.x=512 -> 0..131071 (8 elts each)
    if (*flag) {
        ((u16x8*)d)[i8] = ((const u16x8*)s)[i8];
    } else {
        const float4* s4 = (const float4*)s;
        float4 a = s4[i8 * 2], b = s4[i8 * 2 + 1];
        u16x8 o;
        o[0] = f2bf(a.x); o[1] = f2bf(a.y); o[2] = f2bf(a.z); o[3] = f2bf(a.w);
        o[4] = f2bf(b.x); o[5] = f2bf(b.y); o[6] = f2bf(b.z); o[7] = f2bf(b.w);
        ((u16x8*)d)[i8] = o;
    }
}

// ---------------- time-shift mix (+optional sigmoid) -> bf16 ----------------
__global__ void prep(const void* __restrict__ xb, size_t xoff,
                     const float* __restrict__ tm,
                     unsigned short* __restrict__ outb, int do_sigmoid,
                     const unsigned* __restrict__ flag) {
    size_t i8 = (size_t)blockIdx.x * 256 + threadIdx.x;  // 8-element chunk index
    int d8 = (int)(i8 & 127);
    size_t row = i8 >> 7;
    int t = (int)(row & (SEQ - 1));
    float xv[8], xs[8];
    if (*flag) {
        const unsigned short* x = (const unsigned short*)xb + xoff;
        u16x8 a = ((const u16x8*)x)[i8];
#pragma unroll
        for (int j = 0; j < 8; ++j) xv[j] = bf2f(a[j]);
        if (t > 0) {
            u16x8 b = ((const u16x8*)x)[i8 - 128];
#pragma unroll
            for (int j = 0; j < 8; ++j) xs[j] = bf2f(b[j]);
        } else {
#pragma unroll
            for (int j = 0; j < 8; ++j) xs[j] = 0.f;
        }
    } else {
        const float* x = (const float*)xb + xoff;
        const float4* x4 = (const float4*)x;
        float4 a0 = x4[i8 * 2], a1 = x4[i8 * 2 + 1];
        xv[0]=a0.x; xv[1]=a0.y; xv[2]=a0.z; xv[3]=a0.w;
        xv[4]=a1.x; xv[5]=a1.y; xv[6]=a1.z; xv[7]=a1.w;
        if (t > 0) {
            float4 b0 = x4[i8 * 2 - 256], b1 = x4[i8 * 2 - 255];
            xs[0]=b0.x; xs[1]=b0.y; xs[2]=b0.z; xs[3]=b0.w;
            xs[4]=b1.x; xs[5]=b1.y; xs[6]=b1.z; xs[7]=b1.w;
        } else {
#pragma unroll
            for (int j = 0; j < 8; ++j) xs[j] = 0.f;
        }
    }
    const float4* t4 = (const float4*)tm;
    float4 m0 = t4[d8 * 2], m1 = t4[d8 * 2 + 1];
    float mm[8] = {m0.x, m0.y, m0.z, m0.w, m1.x, m1.y, m1.z, m1.w};
    u16x8 o;
#pragma unroll
    for (int j = 0; j < 8; ++j) {
        float r = xs[j] + mm[j] * (xv[j] - xs[j]);
        if (do_sigmoid) r = 1.f / (1.f + __expf(-r));
        o[j] = f2bf(r);
    }
    ((u16x8*)outb)[i8] = o;
}

// ---------------- bf16 GEMM: C[M,N] = A[M,K] * W[N,K]^T (+fp32 bias) -------------
// m97 structure; epilogue writes bf16 (force_bf16 or flag) else fp32.
__global__ __launch_bounds__(256) void gemm_bt(
    const unsigned short* __restrict__ A,   // [M,K] bf16
    const unsigned short* __restrict__ W,   // [N,K] bf16
    const float* __restrict__ biasf,        // [N] fp32 or nullptr
    void* __restrict__ Cout, size_t coff,   // output base + element offset
    int force_bf16, const unsigned* __restrict__ flag,
    int M, int N, int K)
{
    __shared__ unsigned short sA[128 * 32];
    __shared__ unsigned short sB[128 * 32];

    const int tid = threadIdx.x;
    const int lane = tid & 63;
    const int wv = tid >> 6;
    const int wm = (wv >> 1) * 64;
    const int wn = (wv & 1) * 64;
    const int l15 = lane & 15;
    const int qd = lane >> 4;
    const size_t row0 = (size_t)blockIdx.y * 128;
    const size_t col0 = (size_t)blockIdx.x * 128;

    f32x4 acc[4][4];
#pragma unroll
    for (int i = 0; i < 4; ++i)
#pragma unroll
        for (int j = 0; j < 4; ++j)
            acc[i][j] = {0.f, 0.f, 0.f, 0.f};

    for (int k0 = 0; k0 < K; k0 += 32) {
#pragma unroll
        for (int r = 0; r < 2; ++r) {
            int c = r * 256 + tid;
            int row = c >> 2;
            int q8 = (c & 3) * 8;
            __builtin_amdgcn_global_load_lds(
                (const __attribute__((address_space(1))) void*)(A + (row0 + row) * (size_t)K + k0 + q8),
                (__attribute__((address_space(3))) void*)(sA + c * 8), 16, 0, 0);
            __builtin_amdgcn_global_load_lds(
                (const __attribute__((address_space(1))) void*)(W + (col0 + row) * (size_t)K + k0 + q8),
                (__attribute__((address_space(3))) void*)(sB + c * 8), 16, 0, 0);
        }
        __syncthreads();

        short8 af[4], bfr[4];
#pragma unroll
        for (int mt = 0; mt < 4; ++mt)
            af[mt] = *(const short8*)(sA + (wm + mt * 16 + l15) * 32 + qd * 8);
#pragma unroll
        for (int nt = 0; nt < 4; ++nt)
            bfr[nt] = *(const short8*)(sB + (wn + nt * 16 + l15) * 32 + qd * 8);
#pragma unroll
        for (int mt = 0; mt < 4; ++mt)
#pragma unroll
            for (int nt = 0; nt < 4; ++nt)
                acc[mt][nt] = __builtin_amdgcn_mfma_f32_16x16x32_bf16(
                    __builtin_bit_cast(bf16x8, af[mt]),
                    __builtin_bit_cast(bf16x8, bfr[nt]),
                    acc[mt][nt], 0, 0, 0);
        __syncthreads();
    }

    const bool wb16 = force_bf16 || (*flag != 0u);
#pragma unroll
    for (int nt = 0; nt < 4; ++nt) {
        size_t gc = col0 + wn + nt * 16 + l15;
        float bv = biasf ? biasf[gc] : 0.f;
#pragma unroll
        for (int mt = 0; mt < 4; ++mt) {
#pragma unroll
            for (int i = 0; i < 4; ++i) {
                size_t gr = row0 + wm + mt * 16 + qd * 4 + i;
                float vvl = acc[mt][nt][i] + bv;
                size_t idx = coff + gr * (size_t)N + gc;
                if (wb16) ((unsigned short*)Cout)[idx] = f2bf(vvl);
                else      ((float*)Cout)[idx] = vvl;
            }
        }
    }
}

// ---------------- WKV scan, chunk-parallel 3-pass ----------------
__global__ void wkv_pass1(const unsigned short* __restrict__ kk,
                          const unsigned short* __restrict__ vv,
                          const float* __restrict__ uf, const float* __restrict__ wf,
                          float* __restrict__ aloc, float* __restrict__ bloc,
                          float* __restrict__ pp)
{
    int e = blockIdx.x * 256 + threadIdx.x;
    int b = blockIdx.y, c = blockIdx.z;
    float uu = uf[e], ww = wf[e];
    size_t base = ((size_t)(b * SEQ + c * TCH)) * DIMD + e;
    float a = 0.f, bb = 0.f, P = 1.f;
    for (int t = 0; t < TCH; ++t) {
        float kt = bf2f(kk[base + (size_t)t * DIMD]);
        float vt = bf2f(vv[base + (size_t)t * DIMD]);
        float q = fmaxf(uu + kt, ww);
        float e1 = __expf(fminf(-ww - q, 60.f));
        float e2 = __expf(uu + kt - q);
        a = e1 * a + e2 * vt;
        bb = e1 * bb + e2;
        P *= e1;
    }
    P = fminf(fmaxf(P, 0.f), 1e30f);   // NaN/Inf scrub (inert for healthy data)
    size_t si = (size_t)c * NCHG + b * DIMD + e;
    aloc[si] = a; bloc[si] = bb; pp[si] = P;
}

__global__ void wkv_pass2(const float* __restrict__ aloc, const float* __restrict__ bloc,
                          const float* __restrict__ pp,
                          float* __restrict__ ain, float* __restrict__ bin)
{
    int ch = blockIdx.x * 256 + threadIdx.x;
    float a = 0.f, b = 0.f;
    for (int c = 0; c < NCH; ++c) {
        size_t si = (size_t)c * NCHG + ch;
        ain[si] = a; bin[si] = b;
        float P = pp[si];
        a = fmaf(P, a, aloc[si]);
        b = fmaf(P, b, bloc[si]);
    }
}

__global__ void wkv_pass3(const unsigned short* __restrict__ kk,
                          const unsigned short* __restrict__ vv,
                          const unsigned short* __restrict__ rr,
                          const float* __restrict__ uf, const float* __restrict__ wf,
                          const float* __restrict__ ain, const float* __restrict__ bin,
                          unsigned short* __restrict__ ao)
{
    int e = blockIdx.x * 256 + threadIdx.x;
    int b = blockIdx.y, c = blockIdx.z;
    float uu = uf[e], ww = wf[e];
    size_t base = ((size_t)(b * SEQ + c * TCH)) * DIMD + e;
    size_t si = (size_t)c * NCHG + b * DIMD + e;
    float a = ain[si], bb = bin[si];
    for (int t = 0; t < TCH; ++t) {
        size_t gi = base + (size_t)t * DIMD;
        float kt = bf2f(kk[gi]);
        float vt = bf2f(vv[gi]);
        float q = fmaxf(uu + kt, ww);
        float e1 = __expf(fminf(-ww - q, 60.f));
        float e2 = __expf(uu + kt - q);
        a = e1 * a + e2 * vt;
        bb = e1 * bb + e2;
        float wkv = a / fmaxf(bb, 1e-38f);
        float rv = bf2f(rr[gi]);
        ao[gi] = f2bf(wkv * rv);
    }
}

// ---------------- launch ----------------
extern "C" void kernel_launch(void* const* d_in, const int* in_sizes, int n_in,
                              void* d_out, int out_size, void* d_ws, size_t ws_size,
                              hipStream_t stream) {
    const void* x   = d_in[0];
    const void* u   = d_in[1];
    const void* w   = d_in[2];
    const void* tmk = d_in[3];
    const void* tmv = d_in[4];
    const void* tmr = d_in[5];
    const void* Wk  = d_in[6];
    const void* Wv  = d_in[7];
    const void* Wr  = d_in[8];
    const void* Wo  = d_in[9];
    const void* bo  = d_in[10];

    // workspace layout (149 MiB total)
    char* ws = (char*)d_ws;
    const size_t MB = 1ull << 20;
    unsigned* flag = (unsigned*)(ws);                        // 4 B
    float* smallf  = (float*)(ws + 64 * 1024);               // 6x1024 fp32
    unsigned short* Wb = (unsigned short*)(ws + 1 * MB);     // 4x 2 MiB bf16
    unsigned short* mix = (unsigned short*)(ws + 16 * MB);   // 32 MiB
    unsigned short* kk  = (unsigned short*)(ws + 48 * MB);   // 32 MiB
    unsigned short* vvb = (unsigned short*)(ws + 80 * MB);   // 32 MiB
    unsigned short* rrb = (unsigned short*)(ws + 112 * MB);  // 32 MiB
    float* aloc = (float*)(ws + 144 * MB);                   // 1 MiB each
    float* bloc = (float*)(ws + 145 * MB);
    float* pp   = (float*)(ws + 146 * MB);
    float* ain  = (float*)(ws + 147 * MB);
    float* bin  = (float*)(ws + 148 * MB);                   // end 149 MiB
    (void)ws_size; (void)in_sizes; (void)n_in; (void)out_size;

    float* uf   = smallf + 0 * 1024;
    float* wf   = smallf + 1 * 1024;
    float* tmkf = smallf + 2 * 1024;
    float* tmvf = smallf + 3 * 1024;
    float* tmrf = smallf + 4 * 1024;
    float* bof  = smallf + 5 * 1024;
    unsigned short* Wkb = Wb + 0ull * DIMD * DIMD;
    unsigned short* Wvb = Wb + 1ull * DIMD * DIMD;
    unsigned short* Wrb = Wb + 2ull * DIMD * DIMD;
    unsigned short* Wob = Wb + 3ull * DIMD * DIMD;

    detect<<<1, 64, 0, stream>>>((const unsigned*)x, flag);
    cvt_small<<<dim3(4, 6), 256, 0, stream>>>(u, w, tmk, tmv, tmr, bo, smallf, flag);
    cvt_W<<<dim3(512, 4), 256, 0, stream>>>(Wk, Wv, Wr, Wo, Wb, flag);

    dim3 gGemm(DIMD / 128, GTOK / 128);   // (8, 128) per group
    dim3 gScan(DIMD / 256, GB, NCH);      // (4, 4, 64) per group
    const int prepBlocks = GTOK * DIMD / 8 / 256;  // 8192

    for (int g = 0; g < NG; ++g) {
        size_t xoff = (size_t)g * GTOK * DIMD;   // element offset

        prep<<<prepBlocks, 256, 0, stream>>>(x, xoff, tmkf, mix, 0, flag);
        gemm_bt<<<gGemm, 256, 0, stream>>>(mix, Wkb, nullptr, kk, 0, 1, flag, GTOK, DIMD, DIMD);
        prep<<<prepBlocks, 256, 0, stream>>>(x, xoff, tmvf, mix, 0, flag);
        gemm_bt<<<gGemm, 256, 0, stream>>>(mix, Wvb, nullptr, vvb, 0, 1, flag, GTOK, DIMD, DIMD);
        prep<<<prepBlocks, 256, 0, stream>>>(x, xoff, tmrf, mix, 1, flag);
        gemm_bt<<<gGemm, 256, 0, stream>>>(mix, Wrb, nullptr, rrb, 0, 1, flag, GTOK, DIMD, DIMD);

        wkv_pass1<<<gScan, 256, 0, stream>>>(kk, vvb, uf, wf, aloc, bloc, pp);
        wkv_pass2<<<NCHG / 256, 256, 0, stream>>>(aloc, bloc, pp, ain, bin);
        wkv_pass3<<<gScan, 256, 0, stream>>>(kk, vvb, rrb, uf, wf, ain, bin, kk);

        gemm_bt<<<gGemm, 256, 0, stream>>>(kk, Wob, bof, d_out, xoff, 0, flag, GTOK, DIMD, DIMD);
    }
}

// Round 5
// 818.198 us; speedup vs baseline: 1.1986x; 1.1986x over previous
//
#include <hip/hip_runtime.h>

// ---------------- problem constants ----------------
#define DIMD 1024
#define BATCH 8
#define SEQ 4096
#define TCH 64                  // scan chunk length
#define NCH (SEQ / TCH)         // 64 chunks per sequence

typedef short short8 __attribute__((ext_vector_type(8)));
typedef unsigned short u16x8 __attribute__((ext_vector_type(8)));
typedef __bf16 bf16x8 __attribute__((ext_vector_type(8)));
typedef float f32x4 __attribute__((ext_vector_type(4)));

static __device__ __forceinline__ unsigned short f2bf(float f) {
    unsigned int u = __builtin_bit_cast(unsigned int, f);
    u += 0x7FFFu + ((u >> 16) & 1u);   // round-to-nearest-even
    return (unsigned short)(u >> 16);
}
static __device__ __forceinline__ float bf2f(unsigned short s) {
    return __builtin_bit_cast(float, ((unsigned int)s) << 16);
}

// ---------------- dtype detector (validated round 4: detects fp32 here) ---------
__global__ void detect(const unsigned* __restrict__ xw, unsigned* __restrict__ flag) {
    if (threadIdx.x == 0 && blockIdx.x == 0) {
        int cnt = 0;
        for (int i = 0; i < 64; ++i) {
            unsigned lo = xw[i] & 0xFFFFu;
            unsigned e = (lo >> 7) & 0xFFu;
            if ((e >= 0x70u && e <= 0x8Fu) || lo == 0u) ++cnt;
        }
        *flag = (cnt >= 32) ? 1u : 0u;   // 1 = bf16 inputs, 0 = fp32 inputs
    }
}

// ---------------- small param vectors -> fp32 scratch ----------------
// dst layout: [u | w | tmk | tmv | tmr | bo], each 1024 floats
__global__ void cvt_small(const void* __restrict__ s0, const void* __restrict__ s1,
                          const void* __restrict__ s2, const void* __restrict__ s3,
                          const void* __restrict__ s4, const void* __restrict__ s5,
                          float* __restrict__ dst, const unsigned* __restrict__ flag) {
    const void* s;
    switch (blockIdx.y) {
        case 0: s = s0; break; case 1: s = s1; break; case 2: s = s2; break;
        case 3: s = s3; break; case 4: s = s4; break; default: s = s5; break;
    }
    int i = blockIdx.x * 256 + threadIdx.x;   // grid.x = 4 -> 0..1023
    float v = (*flag) ? bf2f(((const unsigned short*)s)[i]) : ((const float*)s)[i];
    dst[blockIdx.y * 1024 + i] = v;
}

// ---------------- weight matrices -> bf16 scratch (4x 2MiB contiguous) ----------
__global__ void cvt_W(const void* __restrict__ s0, const void* __restrict__ s1,
                      const void* __restrict__ s2, const void* __restrict__ s3,
                      unsigned short* __restrict__ dst, const unsigned* __restrict__ flag) {
    const void* s;
    switch (blockIdx.y) {
        case 0: s = s0; break; case 1: s = s1; break;
        case 2: s = s2; break; default: s = s3; break;
    }
    unsigned short* d = dst + (size_t)blockIdx.y * DIMD * DIMD;
    size_t i8 = (size_t)blockIdx.x * 256 + threadIdx.x;   // grid.x=512, 8 elts each
    if (*flag) {
        ((u16x8*)d)[i8] = ((const u16x8*)s)[i8];
    } else {
        const float4* s4 = (const float4*)s;
        float4 a = s4[i8 * 2], b = s4[i8 * 2 + 1];
        u16x8 o;
        o[0] = f2bf(a.x); o[1] = f2bf(a.y); o[2] = f2bf(a.z); o[3] = f2bf(a.w);
        o[4] = f2bf(b.x); o[5] = f2bf(b.y); o[6] = f2bf(b.z); o[7] = f2bf(b.w);
        ((u16x8*)d)[i8] = o;
    }
}

// ---------------- fused time-shift mix: writes mixk/mixv/mixr in one x pass -----
__global__ void prep3(const void* __restrict__ xb, size_t xoff,
                      const float* __restrict__ tmk, const float* __restrict__ tmv,
                      const float* __restrict__ tmr,
                      unsigned short* __restrict__ mix3, size_t mstride,
                      const unsigned* __restrict__ flag) {
    size_t i8 = (size_t)blockIdx.x * 256 + threadIdx.x;  // 8-element chunk index
    int d8 = (int)(i8 & 127);
    size_t row = i8 >> 7;
    int t = (int)(row & (SEQ - 1));
    float xv[8], xs[8];
    if (*flag) {
        const unsigned short* x = (const unsigned short*)xb + xoff;
        u16x8 a = ((const u16x8*)x)[i8];
#pragma unroll
        for (int j = 0; j < 8; ++j) xv[j] = bf2f(a[j]);
        if (t > 0) {
            u16x8 b = ((const u16x8*)x)[i8 - 128];
#pragma unroll
            for (int j = 0; j < 8; ++j) xs[j] = bf2f(b[j]);
        } else {
#pragma unroll
            for (int j = 0; j < 8; ++j) xs[j] = 0.f;
        }
    } else {
        const float* x = (const float*)xb + xoff;
        const float4* x4 = (const float4*)x;
        float4 a0 = x4[i8 * 2], a1 = x4[i8 * 2 + 1];
        xv[0]=a0.x; xv[1]=a0.y; xv[2]=a0.z; xv[3]=a0.w;
        xv[4]=a1.x; xv[5]=a1.y; xv[6]=a1.z; xv[7]=a1.w;
        if (t > 0) {
            float4 b0 = x4[i8 * 2 - 256], b1 = x4[i8 * 2 - 255];
            xs[0]=b0.x; xs[1]=b0.y; xs[2]=b0.z; xs[3]=b0.w;
            xs[4]=b1.x; xs[5]=b1.y; xs[6]=b1.z; xs[7]=b1.w;
        } else {
#pragma unroll
            for (int j = 0; j < 8; ++j) xs[j] = 0.f;
        }
    }
    const float4* k4 = (const float4*)tmk;
    const float4* v4 = (const float4*)tmv;
    const float4* r4 = (const float4*)tmr;
    float4 mk0 = k4[d8*2], mk1 = k4[d8*2+1];
    float4 mv0 = v4[d8*2], mv1 = v4[d8*2+1];
    float4 mr0 = r4[d8*2], mr1 = r4[d8*2+1];
    float mk[8] = {mk0.x,mk0.y,mk0.z,mk0.w, mk1.x,mk1.y,mk1.z,mk1.w};
    float mv[8] = {mv0.x,mv0.y,mv0.z,mv0.w, mv1.x,mv1.y,mv1.z,mv1.w};
    float mr[8] = {mr0.x,mr0.y,mr0.z,mr0.w, mr1.x,mr1.y,mr1.z,mr1.w};
    u16x8 ok, ov, orr;
#pragma unroll
    for (int j = 0; j < 8; ++j) {
        float dxy = xv[j] - xs[j];
        ok[j] = f2bf(xs[j] + mk[j] * dxy);
        ov[j] = f2bf(xs[j] + mv[j] * dxy);
        float r = xs[j] + mr[j] * dxy;
        orr[j] = f2bf(1.f / (1.f + __expf(-r)));
    }
    ((u16x8*)(mix3))[i8] = ok;
    ((u16x8*)(mix3 + mstride))[i8] = ov;
    ((u16x8*)(mix3 + 2 * mstride))[i8] = orr;
}

// ---------------- fused bf16 GEMM: C[M,N]=A[M,K]*W[N,K]^T, K=N=1024 -------------
// nx col-tiles (24 => three matrices selected by bx>>3; 8 => single matrix).
// XCD class swizzle: blocks of class (id&7) handle rows by ≡ cls (mod 8), x-inner.
// BK=64, XOR-swizzled LDS staging (conflict-free ds_read_b128), 32 MFMA/barrier.
__global__ __launch_bounds__(256) void gemm_fused(
    const unsigned short* __restrict__ Aall,  // [nmat][M][1024] bf16
    const unsigned short* __restrict__ Wall,  // [nmat][1024][1024] bf16
    const float* __restrict__ biasf,          // [1024] fp32 or nullptr
    void* __restrict__ Cout, size_t coff,     // element offset into Cout
    int M, int nx, int force_bf16, const unsigned* __restrict__ flag)
{
    __shared__ unsigned short sA[128 * 64];
    __shared__ unsigned short sB[128 * 64];

    const int tid = threadIdx.x;
    const int lane = tid & 63;
    const int wv = tid >> 6;
    const int wm = (wv >> 1) * 64;
    const int wn = (wv & 1) * 64;
    const int l15 = lane & 15;
    const int qd = lane >> 4;

    const int id = blockIdx.x;
    const int cls = id & 7;
    const int sub = id >> 3;
    const int bx = sub % nx;
    const int by = cls + 8 * (sub / nx);
    const int which = bx >> 3;
    const unsigned short* A  = Aall + (size_t)which * M * DIMD;
    const unsigned short* Wp = Wall + (size_t)which * DIMD * DIMD;
    const size_t row0 = (size_t)by * 128;
    const size_t col0 = (size_t)(bx & 7) * 128;

    f32x4 acc[4][4];
#pragma unroll
    for (int i = 0; i < 4; ++i)
#pragma unroll
        for (int j = 0; j < 4; ++j)
            acc[i][j] = {0.f, 0.f, 0.f, 0.f};

    for (int k0 = 0; k0 < DIMD; k0 += 64) {
#pragma unroll
        for (int i = 0; i < 4; ++i) {
            int c = i * 256 + tid;            // 0..1023 chunks of 8 bf16 (16 B)
            int row = c >> 3;
            int jj = c & 7;
            int kA = ((jj ^ (row & 7)) * 8);  // XOR swizzle on the GLOBAL k offset
            __builtin_amdgcn_global_load_lds(
                (const __attribute__((address_space(1))) void*)(A + (row0 + row) * (size_t)DIMD + k0 + kA),
                (__attribute__((address_space(3))) void*)(sA + c * 8), 16, 0, 0);
            __builtin_amdgcn_global_load_lds(
                (const __attribute__((address_space(1))) void*)(Wp + (col0 + row) * (size_t)DIMD + k0 + kA),
                (__attribute__((address_space(3))) void*)(sB + c * 8), 16, 0, 0);
        }
        __syncthreads();

#pragma unroll
        for (int kh = 0; kh < 2; ++kh) {
            short8 af[4], bfr[4];
#pragma unroll
            for (int mt = 0; mt < 4; ++mt) {
                int r = wm + mt * 16 + l15;
                int j = (kh * 4 + qd) ^ (r & 7);
                af[mt] = *(const short8*)(sA + r * 64 + j * 8);
            }
#pragma unroll
            for (int nt = 0; nt < 4; ++nt) {
                int r = wn + nt * 16 + l15;
                int j = (kh * 4 + qd) ^ (r & 7);
                bfr[nt] = *(const short8*)(sB + r * 64 + j * 8);
            }
#pragma unroll
            for (int mt = 0; mt < 4; ++mt)
#pragma unroll
                for (int nt = 0; nt < 4; ++nt)
                    acc[mt][nt] = __builtin_amdgcn_mfma_f32_16x16x32_bf16(
                        __builtin_bit_cast(bf16x8, af[mt]),
                        __builtin_bit_cast(bf16x8, bfr[nt]),
                        acc[mt][nt], 0, 0, 0);
        }
        __syncthreads();
    }

    const bool wb16 = force_bf16 || (*flag != 0u);
    const size_t cbase = coff + (size_t)which * M * DIMD;
#pragma unroll
    for (int nt = 0; nt < 4; ++nt) {
        size_t gc = col0 + wn + nt * 16 + l15;
        float bv = biasf ? biasf[gc] : 0.f;
#pragma unroll
        for (int mt = 0; mt < 4; ++mt) {
#pragma unroll
            for (int i = 0; i < 4; ++i) {
                size_t gr = row0 + wm + mt * 16 + qd * 4 + i;
                float vvl = acc[mt][nt][i] + bv;
                size_t idx = cbase + gr * (size_t)DIMD + gc;
                if (wb16) ((unsigned short*)Cout)[idx] = f2bf(vvl);
                else      ((float*)Cout)[idx] = vvl;
            }
        }
    }
}

// ---------------- WKV scan, chunk-parallel 3-pass ----------------
__global__ void wkv_pass1(const unsigned short* __restrict__ kk,
                          const unsigned short* __restrict__ vv,
                          const float* __restrict__ uf, const float* __restrict__ wf,
                          float* __restrict__ aloc, float* __restrict__ bloc,
                          float* __restrict__ pp, int nchan)
{
    int e = blockIdx.x * 256 + threadIdx.x;
    int b = blockIdx.y, c = blockIdx.z;
    float uu = uf[e], ww = wf[e];
    size_t base = ((size_t)(b * SEQ + c * TCH)) * DIMD + e;
    float a = 0.f, bb = 0.f, P = 1.f;
    for (int t = 0; t < TCH; ++t) {
        float kt = bf2f(kk[base + (size_t)t * DIMD]);
        float vt = bf2f(vv[base + (size_t)t * DIMD]);
        float q = fmaxf(uu + kt, ww);
        float e1 = __expf(fminf(-ww - q, 60.f));
        float e2 = __expf(uu + kt - q);
        a = e1 * a + e2 * vt;
        bb = e1 * bb + e2;
        P *= e1;
    }
    P = fminf(fmaxf(P, 0.f), 1e30f);
    size_t si = (size_t)c * nchan + b * DIMD + e;
    aloc[si] = a; bloc[si] = bb; pp[si] = P;
}

__global__ void wkv_pass2(const float* __restrict__ aloc, const float* __restrict__ bloc,
                          const float* __restrict__ pp,
                          float* __restrict__ ain, float* __restrict__ bin, int nchan)
{
    int ch = blockIdx.x * 256 + threadIdx.x;
    float a = 0.f, b = 0.f;
    for (int c = 0; c < NCH; ++c) {
        size_t si = (size_t)c * nchan + ch;
        ain[si] = a; bin[si] = b;
        float P = pp[si];
        a = fmaf(P, a, aloc[si]);
        b = fmaf(P, b, bloc[si]);
    }
}

__global__ void wkv_pass3(const unsigned short* __restrict__ kk,
                          const unsigned short* __restrict__ vv,
                          const unsigned short* __restrict__ rr,
                          const float* __restrict__ uf, const float* __restrict__ wf,
                          const float* __restrict__ ain, const float* __restrict__ bin,
                          unsigned short* __restrict__ ao, int nchan)
{
    int e = blockIdx.x * 256 + threadIdx.x;
    int b = blockIdx.y, c = blockIdx.z;
    float uu = uf[e], ww = wf[e];
    size_t base = ((size_t)(b * SEQ + c * TCH)) * DIMD + e;
    size_t si = (size_t)c * nchan + b * DIMD + e;
    float a = ain[si], bb = bin[si];
    for (int t = 0; t < TCH; ++t) {
        size_t gi = base + (size_t)t * DIMD;
        float kt = bf2f(kk[gi]);
        float vt = bf2f(vv[gi]);
        float q = fmaxf(uu + kt, ww);
        float e1 = __expf(fminf(-ww - q, 60.f));
        float e2 = __expf(uu + kt - q);
        a = e1 * a + e2 * vt;
        bb = e1 * bb + e2;
        float wkv = a / fmaxf(bb, 1e-38f);
        float rv = bf2f(rr[gi]);
        ao[gi] = f2bf(wkv * rv);
    }
}

// ---------------- launch ----------------
extern "C" void kernel_launch(void* const* d_in, const int* in_sizes, int n_in,
                              void* d_out, int out_size, void* d_ws, size_t ws_size,
                              hipStream_t stream) {
    const void* x   = d_in[0];
    const void* u   = d_in[1];
    const void* w   = d_in[2];
    const void* tmk = d_in[3];
    const void* tmv = d_in[4];
    const void* tmr = d_in[5];
    const void* Wk  = d_in[6];
    const void* Wv  = d_in[7];
    const void* Wr  = d_in[8];
    const void* Wo  = d_in[9];
    const void* bo  = d_in[10];
    (void)in_sizes; (void)n_in; (void)out_size;

    const size_t MB = 1ull << 20;
    // host-constant grouping decision (same every call -> graph-safe)
    int nb;                                    // batches per group
    if      (ws_size >= 432 * MB) nb = 8;      // full batch, one pass
    else if (ws_size >= 124 * MB) nb = 2;      // 4 groups (validated: 149 MiB OK)
    else                          nb = 1;      // 8 groups (~66 MiB)
    const int ngroups = BATCH / nb;
    const size_t Mg = (size_t)nb * SEQ;        // tokens per group
    const int nchan = nb * DIMD;

    char* ws = (char*)d_ws;
    unsigned* flag = (unsigned*)(ws);
    float* smallf  = (float*)(ws + 64 * 1024);           // 6x1024 fp32
    unsigned short* Wb = (unsigned short*)(ws + 1 * MB); // 4x 2 MiB (Wk,Wv,Wr,Wo)
    unsigned short* mix3 = (unsigned short*)(ws + 16 * MB);
    size_t matB = Mg * DIMD * sizeof(unsigned short);    // bytes per [Mg,1024] bf16
    unsigned short* kvr = (unsigned short*)((char*)mix3 + 3 * matB);
    char* sc = (char*)kvr + 3 * matB;
    size_t scanB = (size_t)NCH * nchan * sizeof(float);
    float* aloc = (float*)(sc + 0 * scanB);
    float* bloc = (float*)(sc + 1 * scanB);
    float* pp   = (float*)(sc + 2 * scanB);
    float* ain  = (float*)(sc + 3 * scanB);
    float* bin  = (float*)(sc + 4 * scanB);

    float* uf   = smallf + 0 * 1024;
    float* wf   = smallf + 1 * 1024;
    float* tmkf = smallf + 2 * 1024;
    float* tmvf = smallf + 3 * 1024;
    float* tmrf = smallf + 4 * 1024;
    float* bof  = smallf + 5 * 1024;
    unsigned short* Wob = Wb + 3ull * DIMD * DIMD;

    detect<<<1, 64, 0, stream>>>((const unsigned*)x, flag);
    cvt_small<<<dim3(4, 6), 256, 0, stream>>>(u, w, tmk, tmv, tmr, bo, smallf, flag);
    cvt_W<<<dim3(512, 4), 256, 0, stream>>>(Wk, Wv, Wr, Wo, Wb, flag);

    const size_t mstride = Mg * DIMD;          // elements per matrix slot
    unsigned short* kk  = kvr;
    unsigned short* vvb = kvr + mstride;
    unsigned short* rrb = kvr + 2 * mstride;
    const int ny = (int)(Mg / 128);
    dim3 gScan(DIMD / 256, nb, NCH);

    for (int g = 0; g < ngroups; ++g) {
        size_t xoff = (size_t)g * Mg * DIMD;   // element offset

        prep3<<<(int)(Mg * DIMD / 8 / 256), 256, 0, stream>>>(
            x, xoff, tmkf, tmvf, tmrf, mix3, mstride, flag);
        gemm_fused<<<24 * ny, 256, 0, stream>>>(
            mix3, Wb, nullptr, kvr, 0, (int)Mg, 24, 1, flag);

        wkv_pass1<<<gScan, 256, 0, stream>>>(kk, vvb, uf, wf, aloc, bloc, pp, nchan);
        wkv_pass2<<<nchan / 256, 256, 0, stream>>>(aloc, bloc, pp, ain, bin, nchan);
        wkv_pass3<<<gScan, 256, 0, stream>>>(kk, vvb, rrb, uf, wf, ain, bin, kk, nchan);

        gemm_fused<<<8 * ny, 256, 0, stream>>>(
            kk, Wob, bof, d_out, xoff, (int)Mg, 8, 0, flag);
    }
}